// Round 1
// baseline (729.777 us; speedup 1.0000x reference)
//
#include <hip/hip_runtime.h>

#define D 64

// --- degree histogram over dst -------------------------------------------
__global__ void count_deg_kernel(const int* __restrict__ dst, int* __restrict__ deg, int nE) {
    int e = blockIdx.x * blockDim.x + threadIdx.x;
    if (e < nE) atomicAdd(&deg[dst[e]], 1);
}

__global__ void make_inv_kernel(const int* __restrict__ deg, float* __restrict__ inv, int N) {
    int i = blockIdx.x * blockDim.x + threadIdx.x;
    if (i < N) inv[i] = 1.0f / (float)(deg[i] + 1);
}

// --- edge scatter: agg[dst] += h[src], 64 lanes = 64 features per edge ----
__global__ void scatter_add_kernel(const float* __restrict__ h, const int* __restrict__ src,
                                   const int* __restrict__ dst, float* __restrict__ agg, int nE) {
    int t = blockIdx.x * blockDim.x + threadIdx.x;
    int e = t >> 6;      // edge index
    int f = t & 63;      // feature lane
    if (e < nE) {
        int s = src[e];
        int d = dst[e];
        atomicAdd(&agg[d * D + f], h[s * D + f]);
    }
}

// --- combine + GEMM: out = relu?(((agg+h)*inv) @ W + b) -------------------
// W (64x64 fp32, 16KB) staged in LDS; 4 nodes per block pass, thread j
// computes out[i][j] via 64-FMA inner loop. Ws[k*64+j] -> 2-way bank
// aliasing (free); tmp[local][k] -> broadcast (free).
__global__ __launch_bounds__(256) void combine_gemm_kernel(
    const float* __restrict__ agg, const float* __restrict__ h,
    const float* __restrict__ inv, const float* __restrict__ W,
    const float* __restrict__ bias, float* __restrict__ out,
    int N, int do_relu)
{
    __shared__ float Ws[D * D];
    __shared__ float tmp[4][D];
    for (int i = threadIdx.x; i < D * D; i += 256) Ws[i] = W[i];
    int j = threadIdx.x & 63;       // output feature
    int local = threadIdx.x >> 6;   // node slot within block (0..3)
    float bj = bias[j];
    __syncthreads();

    for (int base = blockIdx.x * 4; base < N; base += gridDim.x * 4) {
        int i = base + local;
        if (i < N) {
            tmp[local][j] = (agg[i * D + j] + h[i * D + j]) * inv[i];
        }
        __syncthreads();
        if (i < N) {
            float acc = bj;
            #pragma unroll
            for (int k = 0; k < D; ++k) {
                acc = fmaf(tmp[local][k], Ws[k * D + j], acc);
            }
            if (do_relu) acc = fmaxf(acc, 0.0f);
            out[i * D + j] = acc;
        }
        __syncthreads();
    }
}

extern "C" void kernel_launch(void* const* d_in, const int* in_sizes, int n_in,
                              void* d_out, int out_size, void* d_ws, size_t ws_size,
                              hipStream_t stream) {
    const float* x  = (const float*)d_in[0];
    const int*   src = (const int*)d_in[1];
    const int*   dst = (const int*)d_in[2];
    const float* W0 = (const float*)d_in[3];
    const float* b0 = (const float*)d_in[4];
    const float* W1 = (const float*)d_in[5];
    const float* b1 = (const float*)d_in[6];
    const float* W2 = (const float*)d_in[7];
    const float* b2 = (const float*)d_in[8];
    float* out = (float*)d_out;

    const int N = in_sizes[0] / D;   // 50000
    const int E = in_sizes[1];       // 800000

    // workspace layout (all 256B-aligned): inv | deg | agg | h1 | h2  (~38.8MB)
    char* ws = (char*)d_ws;
    size_t off = 0;
    auto alloc = [&](size_t bytes) -> void* {
        void* p = ws + off;
        off = (off + bytes + 255) & ~(size_t)255;
        return p;
    };
    float* inv = (float*)alloc((size_t)N * sizeof(float));
    int*   deg = (int*)  alloc((size_t)N * sizeof(int));
    float* agg = (float*)alloc((size_t)N * D * sizeof(float));
    float* h1  = (float*)alloc((size_t)N * D * sizeof(float));
    float* h2  = (float*)alloc((size_t)N * D * sizeof(float));

    // degree -> inv (once; constant across layers)
    hipMemsetAsync(deg, 0, (size_t)N * sizeof(int), stream);
    count_deg_kernel<<<(E + 255) / 256, 256, 0, stream>>>(dst, deg, E);
    make_inv_kernel<<<(N + 255) / 256, 256, 0, stream>>>(deg, inv, N);

    const int scatter_blocks = (E * D + 255) / 256;  // 200000 blocks
    const int gemm_blocks = 1024;

    // layer 0: x -> h1 (relu)
    hipMemsetAsync(agg, 0, (size_t)N * D * sizeof(float), stream);
    scatter_add_kernel<<<scatter_blocks, 256, 0, stream>>>(x, src, dst, agg, E);
    combine_gemm_kernel<<<gemm_blocks, 256, 0, stream>>>(agg, x, inv, W0, b0, h1, N, 1);

    // layer 1: h1 -> h2 (relu)
    hipMemsetAsync(agg, 0, (size_t)N * D * sizeof(float), stream);
    scatter_add_kernel<<<scatter_blocks, 256, 0, stream>>>(h1, src, dst, agg, E);
    combine_gemm_kernel<<<gemm_blocks, 256, 0, stream>>>(agg, h1, inv, W1, b1, h2, N, 1);

    // layer 2: h2 -> out (no relu)
    hipMemsetAsync(agg, 0, (size_t)N * D * sizeof(float), stream);
    scatter_add_kernel<<<scatter_blocks, 256, 0, stream>>>(h2, src, dst, agg, E);
    combine_gemm_kernel<<<gemm_blocks, 256, 0, stream>>>(agg, h2, inv, W2, b2, out, N, 0);
}

// Round 2
// 458.754 us; speedup vs baseline: 1.5908x; 1.5908x over previous
//
#include <hip/hip_runtime.h>

#define D 64

// --- degree histogram over dst (int atomics, cheap) -----------------------
__global__ void count_deg_kernel(const int* __restrict__ dst, int* __restrict__ deg, int nE) {
    int e = blockIdx.x * blockDim.x + threadIdx.x;
    if (e < nE) atomicAdd(&deg[dst[e]], 1);
}

// --- single-block exclusive scan over deg -> row_ptr (+cursor copy) -------
__global__ __launch_bounds__(1024) void scan_kernel(const int* __restrict__ deg,
                                                    int* __restrict__ row_ptr,
                                                    int* __restrict__ cursor, int N) {
    __shared__ int sums[1024];
    int t = threadIdx.x;
    int chunk = (N + 1023) >> 10;
    int lo = t * chunk;
    int hi = min(N, lo + chunk);
    int s = 0;
    for (int i = lo; i < hi; ++i) s += deg[i];
    sums[t] = s;
    __syncthreads();
    // Hillis-Steele inclusive scan over 1024 partial sums
    for (int d = 1; d < 1024; d <<= 1) {
        int v = (t >= d) ? sums[t - d] : 0;
        __syncthreads();
        sums[t] += v;
        __syncthreads();
    }
    int run = sums[t] - s;  // exclusive prefix of this thread's chunk
    for (int i = lo; i < hi; ++i) {
        row_ptr[i] = run;
        cursor[i] = run;
        run += deg[i];
    }
    if (t == 1023) row_ptr[N] = sums[1023];
}

// --- bucket edges by dst: col[pos] = src ----------------------------------
__global__ void fill_csr_kernel(const int* __restrict__ src, const int* __restrict__ dst,
                                int* __restrict__ cursor, int* __restrict__ col, int nE) {
    int e = blockIdx.x * blockDim.x + threadIdx.x;
    if (e < nE) {
        int d = dst[e];
        int p = atomicAdd(&cursor[d], 1);
        col[p] = src[e];
    }
}

// --- fused layer: out = relu?( ((sum_{s in N(i)} h[s] + h[i]) / (deg+1)) @ W + b )
// One wave per node (lane = feature). Gather h[src] rows coalesced (256B/edge),
// accumulate in register -> normalize -> LDS row broadcast -> 64-FMA GEMM with
// W staged in LDS. Ws[k*64+lane]: 2 lanes/bank = free; tmp[w][k]: broadcast = free.
__global__ __launch_bounds__(256) void sage_layer_kernel(
    const float* __restrict__ h, const int* __restrict__ row_ptr,
    const int* __restrict__ col, const float* __restrict__ W,
    const float* __restrict__ bias, float* __restrict__ out,
    int N, int do_relu)
{
    __shared__ float Ws[D * D];
    __shared__ float tmp[4][D];
    for (int i = threadIdx.x; i < D * D; i += 256) Ws[i] = W[i];
    const int lane = threadIdx.x & 63;
    const int w = threadIdx.x >> 6;
    float bj = bias[lane];
    __syncthreads();

    for (int base = blockIdx.x * 4; base < N; base += gridDim.x * 4) {
        int i = base + w;
        if (i < N) {
            int rs = row_ptr[i];
            int re = row_ptr[i + 1];
            float acc = h[(size_t)i * D + lane];   // self term
            for (int e0 = rs; e0 < re; e0 += 64) {
                int ee = e0 + lane;
                int idx = (ee < re) ? col[ee] : 0;  // vector-load 64 edge indices
                int cnt = min(64, re - e0);
                #pragma unroll 4
                for (int t = 0; t < cnt; ++t) {
                    int s = __shfl(idx, t);
                    acc += h[(size_t)s * D + lane];
                }
            }
            float invd = 1.0f / (float)(re - rs + 1);
            tmp[w][lane] = acc * invd;
        }
        __syncthreads();
        if (i < N) {
            float o = bj;
            #pragma unroll 8
            for (int k = 0; k < D; ++k) {
                o = fmaf(tmp[w][k], Ws[k * D + lane], o);
            }
            if (do_relu) o = fmaxf(o, 0.0f);
            out[(size_t)i * D + lane] = o;
        }
        __syncthreads();
    }
}

extern "C" void kernel_launch(void* const* d_in, const int* in_sizes, int n_in,
                              void* d_out, int out_size, void* d_ws, size_t ws_size,
                              hipStream_t stream) {
    const float* x   = (const float*)d_in[0];
    const int*   src = (const int*)d_in[1];
    const int*   dst = (const int*)d_in[2];
    const float* W0  = (const float*)d_in[3];
    const float* b0  = (const float*)d_in[4];
    const float* W1  = (const float*)d_in[5];
    const float* b1  = (const float*)d_in[6];
    const float* W2  = (const float*)d_in[7];
    const float* b2  = (const float*)d_in[8];
    float* out = (float*)d_out;

    const int N = in_sizes[0] / D;   // 50000
    const int E = in_sizes[1];       // 800000

    // workspace: deg | row_ptr | cursor | col | h1 | h2  (~29.4 MB)
    char* ws = (char*)d_ws;
    size_t off = 0;
    auto alloc = [&](size_t bytes) -> void* {
        void* p = ws + off;
        off = (off + bytes + 255) & ~(size_t)255;
        return p;
    };
    int*   deg     = (int*)  alloc((size_t)N * sizeof(int));
    int*   row_ptr = (int*)  alloc((size_t)(N + 1) * sizeof(int));
    int*   cursor  = (int*)  alloc((size_t)N * sizeof(int));
    int*   col     = (int*)  alloc((size_t)E * sizeof(int));
    float* h1      = (float*)alloc((size_t)N * D * sizeof(float));
    float* h2      = (float*)alloc((size_t)N * D * sizeof(float));

    // --- build CSR (once per call; reused by all 3 layers) ---
    hipMemsetAsync(deg, 0, (size_t)N * sizeof(int), stream);
    count_deg_kernel<<<(E + 255) / 256, 256, 0, stream>>>(dst, deg, E);
    scan_kernel<<<1, 1024, 0, stream>>>(deg, row_ptr, cursor, N);
    fill_csr_kernel<<<(E + 255) / 256, 256, 0, stream>>>(src, dst, cursor, col, E);

    const int layer_blocks = 2048;  // grid-stride; 8 blocks/CU, LDS ~17KB each

    sage_layer_kernel<<<layer_blocks, 256, 0, stream>>>(x,  row_ptr, col, W0, b0, h1,  N, 1);
    sage_layer_kernel<<<layer_blocks, 256, 0, stream>>>(h1, row_ptr, col, W1, b1, h2,  N, 1);
    sage_layer_kernel<<<layer_blocks, 256, 0, stream>>>(h2, row_ptr, col, W2, b2, out, N, 0);
}

// Round 3
// 358.587 us; speedup vs baseline: 2.0351x; 1.2793x over previous
//
#include <hip/hip_runtime.h>

#define D 64

// --- degree histogram over dst (int atomics, cheap) -----------------------
__global__ void count_deg_kernel(const int* __restrict__ dst, int* __restrict__ deg, int nE) {
    int e = blockIdx.x * blockDim.x + threadIdx.x;
    if (e < nE) atomicAdd(&deg[dst[e]], 1);
}

// --- hierarchical exclusive scan: A (per-block tile scan) ------------------
__global__ __launch_bounds__(256) void scan_a_kernel(const int* __restrict__ deg,
                                                     int* __restrict__ row_ptr,
                                                     int* __restrict__ blocksums, int N) {
    __shared__ int s[256];
    int t = threadIdx.x;
    int i = blockIdx.x * 256 + t;
    int v = (i < N) ? deg[i] : 0;
    s[t] = v;
    __syncthreads();
    #pragma unroll
    for (int d = 1; d < 256; d <<= 1) {
        int u = (t >= d) ? s[t - d] : 0;
        __syncthreads();
        s[t] += u;
        __syncthreads();
    }
    if (i < N) row_ptr[i] = s[t] - v;             // exclusive (block-local)
    if (t == 255) blocksums[blockIdx.x] = s[255]; // block total
}

// --- B: single-block exclusive scan of block sums (nb <= 256) --------------
__global__ __launch_bounds__(256) void scan_b_kernel(int* __restrict__ blocksums,
                                                     int* __restrict__ row_ptr,
                                                     int nb, int N) {
    __shared__ int s[256];
    int t = threadIdx.x;
    int v = (t < nb) ? blocksums[t] : 0;
    s[t] = v;
    __syncthreads();
    #pragma unroll
    for (int d = 1; d < 256; d <<= 1) {
        int u = (t >= d) ? s[t - d] : 0;
        __syncthreads();
        s[t] += u;
        __syncthreads();
    }
    if (t < nb) blocksums[t] = s[t] - v;  // exclusive block offsets
    if (t == 255) row_ptr[N] = s[255];    // total = E
}

// --- C: apply block offsets, emit final row_ptr + cursor -------------------
__global__ __launch_bounds__(256) void scan_c_kernel(int* __restrict__ row_ptr,
                                                     int* __restrict__ cursor,
                                                     const int* __restrict__ blocksums, int N) {
    int i = blockIdx.x * 256 + threadIdx.x;
    if (i < N) {
        int r = row_ptr[i] + blocksums[blockIdx.x];
        row_ptr[i] = r;
        cursor[i] = r;
    }
}

// --- bucket edges by dst: col[pos] = src ----------------------------------
__global__ void fill_csr_kernel(const int* __restrict__ src, const int* __restrict__ dst,
                                int* __restrict__ cursor, int* __restrict__ col, int nE) {
    int e = blockIdx.x * blockDim.x + threadIdx.x;
    if (e < nE) {
        int d = dst[e];
        int p = atomicAdd(&cursor[d], 1);
        col[p] = src[e];
    }
}

// --- fused layer: out = relu?( ((sum_{s in N(i)} h[s] + h[i]) / (deg+1)) @ W + b )
// One wave per node (lane = feature). Gather h[src] rows coalesced (256B/edge),
// accumulate in register -> normalize -> LDS row broadcast -> 64-FMA GEMM with
// W staged in LDS. Ws[k*64+lane]: 2 lanes/bank = free; tmp[w][k]: broadcast = free.
__global__ __launch_bounds__(256) void sage_layer_kernel(
    const float* __restrict__ h, const int* __restrict__ row_ptr,
    const int* __restrict__ col, const float* __restrict__ W,
    const float* __restrict__ bias, float* __restrict__ out,
    int N, int do_relu)
{
    __shared__ float Ws[D * D];
    __shared__ float tmp[4][D];
    for (int i = threadIdx.x; i < D * D; i += 256) Ws[i] = W[i];
    const int lane = threadIdx.x & 63;
    const int w = threadIdx.x >> 6;
    float bj = bias[lane];
    __syncthreads();

    for (int base = blockIdx.x * 4; base < N; base += gridDim.x * 4) {
        int i = base + w;
        if (i < N) {
            int rs = row_ptr[i];
            int re = row_ptr[i + 1];
            float acc = h[(size_t)i * D + lane];   // self term
            for (int e0 = rs; e0 < re; e0 += 64) {
                int ee = e0 + lane;
                int idx = (ee < re) ? col[ee] : 0;  // vector-load 64 edge indices
                int cnt = min(64, re - e0);
                #pragma unroll 4
                for (int t = 0; t < cnt; ++t) {
                    int s = __shfl(idx, t);
                    acc += h[(size_t)s * D + lane];
                }
            }
            float invd = 1.0f / (float)(re - rs + 1);
            tmp[w][lane] = acc * invd;
        }
        __syncthreads();
        if (i < N) {
            float o = bj;
            #pragma unroll 8
            for (int k = 0; k < D; ++k) {
                o = fmaf(tmp[w][k], Ws[k * D + lane], o);
            }
            if (do_relu) o = fmaxf(o, 0.0f);
            out[(size_t)i * D + lane] = o;
        }
        __syncthreads();
    }
}

extern "C" void kernel_launch(void* const* d_in, const int* in_sizes, int n_in,
                              void* d_out, int out_size, void* d_ws, size_t ws_size,
                              hipStream_t stream) {
    const float* x   = (const float*)d_in[0];
    const int*   src = (const int*)d_in[1];
    const int*   dst = (const int*)d_in[2];
    const float* W0  = (const float*)d_in[3];
    const float* b0  = (const float*)d_in[4];
    const float* W1  = (const float*)d_in[5];
    const float* b1  = (const float*)d_in[6];
    const float* W2  = (const float*)d_in[7];
    const float* b2  = (const float*)d_in[8];
    float* out = (float*)d_out;

    const int N = in_sizes[0] / D;   // 50000
    const int E = in_sizes[1];       // 800000

    const int scan_blocks = (N + 255) / 256;  // 196 (<= 256 required by scan_b)

    // workspace: deg | row_ptr | cursor | blocksums | col | h1 | h2
    char* ws = (char*)d_ws;
    size_t off = 0;
    auto alloc = [&](size_t bytes) -> void* {
        void* p = ws + off;
        off = (off + bytes + 255) & ~(size_t)255;
        return p;
    };
    int*   deg       = (int*)  alloc((size_t)N * sizeof(int));
    int*   row_ptr   = (int*)  alloc((size_t)(N + 1) * sizeof(int));
    int*   cursor    = (int*)  alloc((size_t)N * sizeof(int));
    int*   blocksums = (int*)  alloc((size_t)scan_blocks * sizeof(int));
    int*   col       = (int*)  alloc((size_t)E * sizeof(int));
    float* h1        = (float*)alloc((size_t)N * D * sizeof(float));
    float* h2        = (float*)alloc((size_t)N * D * sizeof(float));

    // --- build CSR (once per call; reused by all 3 layers) ---
    hipMemsetAsync(deg, 0, (size_t)N * sizeof(int), stream);
    count_deg_kernel<<<(E + 255) / 256, 256, 0, stream>>>(dst, deg, E);
    scan_a_kernel<<<scan_blocks, 256, 0, stream>>>(deg, row_ptr, blocksums, N);
    scan_b_kernel<<<1, 256, 0, stream>>>(blocksums, row_ptr, scan_blocks, N);
    scan_c_kernel<<<scan_blocks, 256, 0, stream>>>(row_ptr, cursor, blocksums, N);
    fill_csr_kernel<<<(E + 255) / 256, 256, 0, stream>>>(src, dst, cursor, col, E);

    const int layer_blocks = 2048;  // grid-stride; 8 blocks/CU, LDS ~17KB each

    sage_layer_kernel<<<layer_blocks, 256, 0, stream>>>(x,  row_ptr, col, W0, b0, h1,  N, 1);
    sage_layer_kernel<<<layer_blocks, 256, 0, stream>>>(h1, row_ptr, col, W1, b1, h2,  N, 1);
    sage_layer_kernel<<<layer_blocks, 256, 0, stream>>>(h2, row_ptr, col, W2, b2, out, N, 0);
}

// Round 4
// 321.278 us; speedup vs baseline: 2.2715x; 1.1161x over previous
//
#include <hip/hip_runtime.h>

#define D 64

// --- degree histogram over dst (4 edges/thread, int4 loads) ----------------
__global__ void count_deg_kernel(const int* __restrict__ dst, int* __restrict__ deg, int nE) {
    int e4 = (blockIdx.x * blockDim.x + threadIdx.x) * 4;
    if (e4 + 3 < nE) {
        int4 d = *(const int4*)(dst + e4);
        atomicAdd(&deg[d.x], 1);
        atomicAdd(&deg[d.y], 1);
        atomicAdd(&deg[d.z], 1);
        atomicAdd(&deg[d.w], 1);
    } else {
        for (int e = e4; e < nE; ++e) atomicAdd(&deg[dst[e]], 1);
    }
}

// --- hierarchical exclusive scan: A (per-block tile scan) ------------------
__global__ __launch_bounds__(256) void scan_a_kernel(const int* __restrict__ deg,
                                                     int* __restrict__ row_ptr,
                                                     int* __restrict__ blocksums, int N) {
    __shared__ int s[256];
    int t = threadIdx.x;
    int i = blockIdx.x * 256 + t;
    int v = (i < N) ? deg[i] : 0;
    s[t] = v;
    __syncthreads();
    #pragma unroll
    for (int d = 1; d < 256; d <<= 1) {
        int u = (t >= d) ? s[t - d] : 0;
        __syncthreads();
        s[t] += u;
        __syncthreads();
    }
    if (i < N) row_ptr[i] = s[t] - v;             // exclusive (block-local)
    if (t == 255) blocksums[blockIdx.x] = s[255]; // block total
}

// --- B: single-block exclusive scan of block sums (nb <= 256) --------------
__global__ __launch_bounds__(256) void scan_b_kernel(int* __restrict__ blocksums,
                                                     int* __restrict__ row_ptr,
                                                     int nb, int N) {
    __shared__ int s[256];
    int t = threadIdx.x;
    int v = (t < nb) ? blocksums[t] : 0;
    s[t] = v;
    __syncthreads();
    #pragma unroll
    for (int d = 1; d < 256; d <<= 1) {
        int u = (t >= d) ? s[t - d] : 0;
        __syncthreads();
        s[t] += u;
        __syncthreads();
    }
    if (t < nb) blocksums[t] = s[t] - v;  // exclusive block offsets
    if (t == 255) row_ptr[N] = s[255];    // total = E
}

// --- C: apply block offsets, emit final row_ptr + cursor -------------------
__global__ __launch_bounds__(256) void scan_c_kernel(int* __restrict__ row_ptr,
                                                     int* __restrict__ cursor,
                                                     const int* __restrict__ blocksums, int N) {
    int i = blockIdx.x * 256 + threadIdx.x;
    if (i < N) {
        int r = row_ptr[i] + blocksums[blockIdx.x];
        row_ptr[i] = r;
        cursor[i] = r;
    }
}

// --- bucket edges by dst: col[pos] = src (4 edges/thread) ------------------
__global__ void fill_csr_kernel(const int* __restrict__ src, const int* __restrict__ dst,
                                int* __restrict__ cursor, int* __restrict__ col, int nE) {
    int e4 = (blockIdx.x * blockDim.x + threadIdx.x) * 4;
    if (e4 + 3 < nE) {
        int4 s = *(const int4*)(src + e4);
        int4 d = *(const int4*)(dst + e4);
        col[atomicAdd(&cursor[d.x], 1)] = s.x;
        col[atomicAdd(&cursor[d.y], 1)] = s.y;
        col[atomicAdd(&cursor[d.z], 1)] = s.z;
        col[atomicAdd(&cursor[d.w], 1)] = s.w;
    } else {
        for (int e = e4; e < nE; ++e)
            col[atomicAdd(&cursor[dst[e]], 1)] = src[e];
    }
}

// --- fused layer: out = relu?( ((sum_{s in N(i)} h[s] + h[i]) / (deg+1)) @ W + b )
// One wave per node, NO barriers in the node loop. Scalarized CSR walk:
// rs/re/edge indices forced into SGPRs via readfirstlane/readlane, so the
// gather is global_load_dword(v_laneoff, s[rowbase]) + v_add into 4
// independent accumulators. GEMM: per-lane tv broadcast via readlane (SGPR
// FMA operand) x Ws[k*64+lane] from LDS (2 lanes/bank = free).
__global__ __launch_bounds__(256) void sage_layer_kernel(
    const float* __restrict__ h, const int* __restrict__ row_ptr,
    const int* __restrict__ col, const float* __restrict__ W,
    const float* __restrict__ bias, float* __restrict__ out,
    int N, int do_relu)
{
    __shared__ float Ws[D * D];
    for (int i = threadIdx.x; i < D * D; i += 256) Ws[i] = W[i];
    const int lane = threadIdx.x & 63;
    const int w = threadIdx.x >> 6;
    const float bj = bias[lane];
    __syncthreads();

    const float* hl = h + lane;          // per-lane feature column base
    const int nwaves = gridDim.x * 4;

    for (int i0 = blockIdx.x * 4 + w; i0 < N; i0 += nwaves) {
        const int i  = __builtin_amdgcn_readfirstlane(i0);   // wave-uniform
        const int rs = __builtin_amdgcn_readfirstlane(row_ptr[i]);
        const int re = __builtin_amdgcn_readfirstlane(row_ptr[i + 1]);

        float a0 = hl[(size_t)i * D];    // self term
        float a1 = 0.0f, a2 = 0.0f, a3 = 0.0f;

        for (int e0 = rs; e0 < re; e0 += 64) {
            int ee = e0 + lane;
            int idx = col[(ee < re) ? ee : (re - 1)];  // coalesced 64 indices
            int cnt = min(64, re - e0);                // scalar (re,e0 scalar)
            int t = 0;
            for (; t + 4 <= cnt; t += 4) {
                int s0 = __builtin_amdgcn_readlane(idx, t);
                int s1 = __builtin_amdgcn_readlane(idx, t + 1);
                int s2 = __builtin_amdgcn_readlane(idx, t + 2);
                int s3 = __builtin_amdgcn_readlane(idx, t + 3);
                float v0 = hl[(size_t)s0 * D];
                float v1 = hl[(size_t)s1 * D];
                float v2 = hl[(size_t)s2 * D];
                float v3 = hl[(size_t)s3 * D];
                a0 += v0; a1 += v1; a2 += v2; a3 += v3;
            }
            for (; t < cnt; ++t) {
                int s0 = __builtin_amdgcn_readlane(idx, t);
                a0 += hl[(size_t)s0 * D];
            }
        }

        float tv = ((a0 + a1) + (a2 + a3)) / (float)(re - rs + 1);

        float o = bj;
        #pragma unroll
        for (int k = 0; k < D; ++k) {
            int ti = __builtin_amdgcn_readlane(__float_as_int(tv), k);
            o = fmaf(__int_as_float(ti), Ws[k * D + lane], o);
        }
        if (do_relu) o = fmaxf(o, 0.0f);
        out[(size_t)i * D + lane] = o;
    }
}

extern "C" void kernel_launch(void* const* d_in, const int* in_sizes, int n_in,
                              void* d_out, int out_size, void* d_ws, size_t ws_size,
                              hipStream_t stream) {
    const float* x   = (const float*)d_in[0];
    const int*   src = (const int*)d_in[1];
    const int*   dst = (const int*)d_in[2];
    const float* W0  = (const float*)d_in[3];
    const float* b0  = (const float*)d_in[4];
    const float* W1  = (const float*)d_in[5];
    const float* b1  = (const float*)d_in[6];
    const float* W2  = (const float*)d_in[7];
    const float* b2  = (const float*)d_in[8];
    float* out = (float*)d_out;

    const int N = in_sizes[0] / D;   // 50000
    const int E = in_sizes[1];       // 800000

    const int scan_blocks = (N + 255) / 256;  // 196 (<= 256 required by scan_b)

    // workspace: deg | row_ptr | cursor | blocksums | col | h1 | h2
    char* ws = (char*)d_ws;
    size_t off = 0;
    auto alloc = [&](size_t bytes) -> void* {
        void* p = ws + off;
        off = (off + bytes + 255) & ~(size_t)255;
        return p;
    };
    int*   deg       = (int*)  alloc((size_t)N * sizeof(int));
    int*   row_ptr   = (int*)  alloc((size_t)(N + 1) * sizeof(int));
    int*   cursor    = (int*)  alloc((size_t)N * sizeof(int));
    int*   blocksums = (int*)  alloc((size_t)scan_blocks * sizeof(int));
    int*   col       = (int*)  alloc((size_t)E * sizeof(int));
    float* h1        = (float*)alloc((size_t)N * D * sizeof(float));
    float* h2        = (float*)alloc((size_t)N * D * sizeof(float));

    // --- build CSR (once per call; reused by all 3 layers) ---
    hipMemsetAsync(deg, 0, (size_t)N * sizeof(int), stream);
    const int e4_blocks = (E / 4 + 255) / 256;
    count_deg_kernel<<<e4_blocks, 256, 0, stream>>>(dst, deg, E);
    scan_a_kernel<<<scan_blocks, 256, 0, stream>>>(deg, row_ptr, blocksums, N);
    scan_b_kernel<<<1, 256, 0, stream>>>(blocksums, row_ptr, scan_blocks, N);
    scan_c_kernel<<<scan_blocks, 256, 0, stream>>>(row_ptr, cursor, blocksums, N);
    fill_csr_kernel<<<e4_blocks, 256, 0, stream>>>(src, dst, cursor, col, E);

    const int layer_blocks = 2048;  // 8 blocks/CU (LDS 16KB, low VGPR)

    sage_layer_kernel<<<layer_blocks, 256, 0, stream>>>(x,  row_ptr, col, W0, b0, h1,  N, 1);
    sage_layer_kernel<<<layer_blocks, 256, 0, stream>>>(h1, row_ptr, col, W1, b1, h2,  N, 1);
    sage_layer_kernel<<<layer_blocks, 256, 0, stream>>>(h2, row_ptr, col, W2, b2, out, N, 0);
}

// Round 5
// 301.249 us; speedup vs baseline: 2.4225x; 1.0665x over previous
//
#include <hip/hip_runtime.h>

#define D 64

// --- degree histogram over dst (4 edges/thread, int4 loads) ----------------
__global__ void count_deg_kernel(const int* __restrict__ dst, int* __restrict__ deg, int nE) {
    int e4 = (blockIdx.x * blockDim.x + threadIdx.x) * 4;
    if (e4 + 3 < nE) {
        int4 d = *(const int4*)(dst + e4);
        atomicAdd(&deg[d.x], 1);
        atomicAdd(&deg[d.y], 1);
        atomicAdd(&deg[d.z], 1);
        atomicAdd(&deg[d.w], 1);
    } else {
        for (int e = e4; e < nE; ++e) atomicAdd(&deg[dst[e]], 1);
    }
}

// --- hierarchical exclusive scan: A (per-block tile scan) ------------------
__global__ __launch_bounds__(256) void scan_a_kernel(const int* __restrict__ deg,
                                                     int* __restrict__ row_ptr,
                                                     int* __restrict__ blocksums, int N) {
    __shared__ int s[256];
    int t = threadIdx.x;
    int i = blockIdx.x * 256 + t;
    int v = (i < N) ? deg[i] : 0;
    s[t] = v;
    __syncthreads();
    #pragma unroll
    for (int d = 1; d < 256; d <<= 1) {
        int u = (t >= d) ? s[t - d] : 0;
        __syncthreads();
        s[t] += u;
        __syncthreads();
    }
    if (i < N) row_ptr[i] = s[t] - v;             // exclusive (block-local)
    if (t == 255) blocksums[blockIdx.x] = s[255]; // block total
}

// --- B: single-block exclusive scan of block sums (nb <= 256) --------------
__global__ __launch_bounds__(256) void scan_b_kernel(int* __restrict__ blocksums,
                                                     int* __restrict__ row_ptr,
                                                     int nb, int N) {
    __shared__ int s[256];
    int t = threadIdx.x;
    int v = (t < nb) ? blocksums[t] : 0;
    s[t] = v;
    __syncthreads();
    #pragma unroll
    for (int d = 1; d < 256; d <<= 1) {
        int u = (t >= d) ? s[t - d] : 0;
        __syncthreads();
        s[t] += u;
        __syncthreads();
    }
    if (t < nb) blocksums[t] = s[t] - v;  // exclusive block offsets
    if (t == 255) row_ptr[N] = s[255];    // total = E
}

// --- C: apply block offsets, emit final row_ptr + cursor -------------------
__global__ __launch_bounds__(256) void scan_c_kernel(int* __restrict__ row_ptr,
                                                     int* __restrict__ cursor,
                                                     const int* __restrict__ blocksums, int N) {
    int i = blockIdx.x * 256 + threadIdx.x;
    if (i < N) {
        int r = row_ptr[i] + blocksums[blockIdx.x];
        row_ptr[i] = r;
        cursor[i] = r;
    }
}

// --- bucket edges by dst: col[pos] = src (4 edges/thread) ------------------
__global__ void fill_csr_kernel(const int* __restrict__ src, const int* __restrict__ dst,
                                int* __restrict__ cursor, int* __restrict__ col, int nE) {
    int e4 = (blockIdx.x * blockDim.x + threadIdx.x) * 4;
    if (e4 + 3 < nE) {
        int4 s = *(const int4*)(src + e4);
        int4 d = *(const int4*)(dst + e4);
        col[atomicAdd(&cursor[d.x], 1)] = s.x;
        col[atomicAdd(&cursor[d.y], 1)] = s.y;
        col[atomicAdd(&cursor[d.z], 1)] = s.z;
        col[atomicAdd(&cursor[d.w], 1)] = s.w;
    } else {
        for (int e = e4; e < nE; ++e)
            col[atomicAdd(&cursor[dst[e]], 1)] = src[e];
    }
}

// --- fused layer: out = relu?( ((sum_{s in N(i)} h[s] + h[i]) / (deg+1)) @ W + b )
// One wave per node, zero LDS, zero barriers.
// Gather: 16 lanes x float4 over features; 4 edge-subgroups (lane>>4) -> each
// global_load_dwordx4 covers 4 edges (1KB/wave); main loop keeps 4 loads in
// flight into 4 independent float4 accumulators. Tail: pad lanes clamp to the
// last edge, corrected by subtracting pad * h[col[re-1]] afterward. Reduce
// across subgroups via shfl_xor(16,32).
// GEMM: W column `lane` lives in 64 VGPRs; t[k] broadcast via readlane.
__global__ __launch_bounds__(256, 4) void sage_layer_kernel(
    const float* __restrict__ h, const int* __restrict__ row_ptr,
    const int* __restrict__ col, const float* __restrict__ W,
    const float* __restrict__ bias, float* __restrict__ out,
    int N, int do_relu)
{
    const int lane = threadIdx.x & 63;
    const int sub  = lane >> 4;       // edge subgroup 0..3
    const int fq   = lane & 15;       // feature quad (features 4*fq..4*fq+3)
    const int w    = threadIdx.x >> 6;

    // W columns in registers: Wreg[k] = W[k][lane]
    float Wreg[D];
    #pragma unroll
    for (int k = 0; k < D; ++k) Wreg[k] = W[k * D + lane];
    const float bj = bias[lane];

    const float4* __restrict__ h4 = (const float4*)h;   // row i = h4[i*16 + fq]

    const int nwaves = gridDim.x * 4;
    for (int i0 = blockIdx.x * 4 + w; i0 < N; i0 += nwaves) {
        const int i   = __builtin_amdgcn_readfirstlane(i0);
        const int rs  = __builtin_amdgcn_readfirstlane(row_ptr[i]);
        const int re  = __builtin_amdgcn_readfirstlane(row_ptr[i + 1]);
        const int deg = re - rs;

        float4 a0 = {0,0,0,0}, a1 = {0,0,0,0}, a2 = {0,0,0,0}, a3 = {0,0,0,0};

        for (int e0 = rs; e0 < re; e0 += 64) {
            int ee = e0 + lane;
            int idxv = col[(ee < re) ? ee : (re - 1)];   // 64 indices, coalesced
            int rem = re - e0;                            // scalar
            int steps = (((rem < 64) ? rem : 64) + 3) >> 2;  // scalar 1..16
            int t = 0;
            for (; t + 4 <= steps; t += 4) {
                int base = (t << 2) + sub;
                int s0 = __shfl(idxv, base);
                int s1 = __shfl(idxv, base + 4);
                int s2 = __shfl(idxv, base + 8);
                int s3 = __shfl(idxv, base + 12);
                float4 v0 = h4[(size_t)s0 * 16 + fq];
                float4 v1 = h4[(size_t)s1 * 16 + fq];
                float4 v2 = h4[(size_t)s2 * 16 + fq];
                float4 v3 = h4[(size_t)s3 * 16 + fq];
                a0.x += v0.x; a0.y += v0.y; a0.z += v0.z; a0.w += v0.w;
                a1.x += v1.x; a1.y += v1.y; a1.z += v1.z; a1.w += v1.w;
                a2.x += v2.x; a2.y += v2.y; a2.z += v2.z; a2.w += v2.w;
                a3.x += v3.x; a3.y += v3.y; a3.z += v3.z; a3.w += v3.w;
            }
            for (; t < steps; ++t) {
                int s0 = __shfl(idxv, (t << 2) + sub);
                float4 v0 = h4[(size_t)s0 * 16 + fq];
                a0.x += v0.x; a0.y += v0.y; a0.z += v0.z; a0.w += v0.w;
            }
        }

        // combine step accumulators
        float4 tt;
        tt.x = (a0.x + a1.x) + (a2.x + a3.x);
        tt.y = (a0.y + a1.y) + (a2.y + a3.y);
        tt.z = (a0.z + a1.z) + (a2.z + a3.z);
        tt.w = (a0.w + a1.w) + (a2.w + a3.w);
        // reduce across the 4 edge subgroups (lanes l, l^16, l^32, l^48)
        tt.x += __shfl_xor(tt.x, 16); tt.x += __shfl_xor(tt.x, 32);
        tt.y += __shfl_xor(tt.y, 16); tt.y += __shfl_xor(tt.y, 32);
        tt.z += __shfl_xor(tt.z, 16); tt.z += __shfl_xor(tt.z, 32);
        tt.w += __shfl_xor(tt.w, 16); tt.w += __shfl_xor(tt.w, 32);

        // pad correction: clamped lanes duplicated col[re-1] pad times
        int pad = (-deg) & 3;
        if (deg > 0 && pad) {
            int last = __builtin_amdgcn_readfirstlane(col[re - 1]);
            float4 vl = h4[(size_t)last * 16 + fq];
            float fp = (float)pad;
            tt.x = fmaf(-fp, vl.x, tt.x);
            tt.y = fmaf(-fp, vl.y, tt.y);
            tt.z = fmaf(-fp, vl.z, tt.z);
            tt.w = fmaf(-fp, vl.w, tt.w);
        }

        // self term + normalize
        float4 hs = h4[(size_t)i * 16 + fq];
        float invd = 1.0f / (float)(deg + 1);
        tt.x = (tt.x + hs.x) * invd;
        tt.y = (tt.y + hs.y) * invd;
        tt.z = (tt.z + hs.z) * invd;
        tt.w = (tt.w + hs.w) * invd;

        // GEMM: o[lane] = bj + sum_k t[k] * W[k][lane]
        float o = bj;
        #pragma unroll
        for (int k = 0; k < D; ++k) {
            float comp = ((k & 3) == 0) ? tt.x : ((k & 3) == 1) ? tt.y
                       : ((k & 3) == 2) ? tt.z : tt.w;
            int ti = __builtin_amdgcn_readlane(__float_as_int(comp), k >> 2);
            o = fmaf(__int_as_float(ti), Wreg[k], o);
        }
        if (do_relu) o = fmaxf(o, 0.0f);
        out[(size_t)i * D + lane] = o;
    }
}

extern "C" void kernel_launch(void* const* d_in, const int* in_sizes, int n_in,
                              void* d_out, int out_size, void* d_ws, size_t ws_size,
                              hipStream_t stream) {
    const float* x   = (const float*)d_in[0];
    const int*   src = (const int*)d_in[1];
    const int*   dst = (const int*)d_in[2];
    const float* W0  = (const float*)d_in[3];
    const float* b0  = (const float*)d_in[4];
    const float* W1  = (const float*)d_in[5];
    const float* b1  = (const float*)d_in[6];
    const float* W2  = (const float*)d_in[7];
    const float* b2  = (const float*)d_in[8];
    float* out = (float*)d_out;

    const int N = in_sizes[0] / D;   // 50000
    const int E = in_sizes[1];       // 800000

    const int scan_blocks = (N + 255) / 256;  // 196 (<= 256 required by scan_b)

    // workspace: deg | row_ptr | cursor | blocksums | col | h1 | h2
    char* ws = (char*)d_ws;
    size_t off = 0;
    auto alloc = [&](size_t bytes) -> void* {
        void* p = ws + off;
        off = (off + bytes + 255) & ~(size_t)255;
        return p;
    };
    int*   deg       = (int*)  alloc((size_t)N * sizeof(int));
    int*   row_ptr   = (int*)  alloc((size_t)(N + 1) * sizeof(int));
    int*   cursor    = (int*)  alloc((size_t)N * sizeof(int));
    int*   blocksums = (int*)  alloc((size_t)scan_blocks * sizeof(int));
    int*   col       = (int*)  alloc((size_t)E * sizeof(int));
    float* h1        = (float*)alloc((size_t)N * D * sizeof(float));
    float* h2        = (float*)alloc((size_t)N * D * sizeof(float));

    // --- build CSR (once per call; reused by all 3 layers) ---
    hipMemsetAsync(deg, 0, (size_t)N * sizeof(int), stream);
    const int e4_blocks = (E / 4 + 255) / 256;
    count_deg_kernel<<<e4_blocks, 256, 0, stream>>>(dst, deg, E);
    scan_a_kernel<<<scan_blocks, 256, 0, stream>>>(deg, row_ptr, blocksums, N);
    scan_b_kernel<<<1, 256, 0, stream>>>(blocksums, row_ptr, scan_blocks, N);
    scan_c_kernel<<<scan_blocks, 256, 0, stream>>>(row_ptr, cursor, blocksums, N);
    fill_csr_kernel<<<e4_blocks, 256, 0, stream>>>(src, dst, cursor, col, E);

    const int layer_blocks = 4096;  // no LDS; VGPR-bound occupancy (~16 waves/CU)

    sage_layer_kernel<<<layer_blocks, 256, 0, stream>>>(x,  row_ptr, col, W0, b0, h1,  N, 1);
    sage_layer_kernel<<<layer_blocks, 256, 0, stream>>>(h1, row_ptr, col, W1, b1, h2,  N, 1);
    sage_layer_kernel<<<layer_blocks, 256, 0, stream>>>(h2, row_ptr, col, W2, b2, out, N, 0);
}

// Round 6
// 288.961 us; speedup vs baseline: 2.5255x; 1.0425x over previous
//
#include <hip/hip_runtime.h>

#define D 64

// --- degree histogram over dst (4 edges/thread, int4 loads) ----------------
__global__ void count_deg_kernel(const int* __restrict__ dst, int* __restrict__ deg, int nE) {
    int e4 = (blockIdx.x * blockDim.x + threadIdx.x) * 4;
    if (e4 + 3 < nE) {
        int4 d = *(const int4*)(dst + e4);
        atomicAdd(&deg[d.x], 1);
        atomicAdd(&deg[d.y], 1);
        atomicAdd(&deg[d.z], 1);
        atomicAdd(&deg[d.w], 1);
    } else {
        for (int e = e4; e < nE; ++e) atomicAdd(&deg[dst[e]], 1);
    }
}

// --- hierarchical exclusive scan: A (per-block tile scan) ------------------
__global__ __launch_bounds__(256) void scan_a_kernel(const int* __restrict__ deg,
                                                     int* __restrict__ row_ptr,
                                                     int* __restrict__ blocksums, int N) {
    __shared__ int s[256];
    int t = threadIdx.x;
    int i = blockIdx.x * 256 + t;
    int v = (i < N) ? deg[i] : 0;
    s[t] = v;
    __syncthreads();
    #pragma unroll
    for (int d = 1; d < 256; d <<= 1) {
        int u = (t >= d) ? s[t - d] : 0;
        __syncthreads();
        s[t] += u;
        __syncthreads();
    }
    if (i < N) row_ptr[i] = s[t] - v;             // exclusive (block-local)
    if (t == 255) blocksums[blockIdx.x] = s[255]; // block total
}

// --- B: single-block exclusive scan of block sums (nb <= 256) --------------
__global__ __launch_bounds__(256) void scan_b_kernel(int* __restrict__ blocksums,
                                                     int* __restrict__ row_ptr,
                                                     int nb, int N) {
    __shared__ int s[256];
    int t = threadIdx.x;
    int v = (t < nb) ? blocksums[t] : 0;
    s[t] = v;
    __syncthreads();
    #pragma unroll
    for (int d = 1; d < 256; d <<= 1) {
        int u = (t >= d) ? s[t - d] : 0;
        __syncthreads();
        s[t] += u;
        __syncthreads();
    }
    if (t < nb) blocksums[t] = s[t] - v;  // exclusive block offsets
    if (t == 255) row_ptr[N] = s[255];    // total = E
}

// --- C: apply block offsets, emit final row_ptr + cursor -------------------
__global__ __launch_bounds__(256) void scan_c_kernel(int* __restrict__ row_ptr,
                                                     int* __restrict__ cursor,
                                                     const int* __restrict__ blocksums, int N) {
    int i = blockIdx.x * 256 + threadIdx.x;
    if (i < N) {
        int r = row_ptr[i] + blocksums[blockIdx.x];
        row_ptr[i] = r;
        cursor[i] = r;
    }
}

// --- bucket edges by dst: col[pos] = src, dst-sliced for XCD locality ------
// Slice g = dst in [g*slice, (g+1)*slice); group = blockIdx & 7 which the HW
// round-robins onto XCD g. All col-writes of a slice then come from ONE L2,
// so each 64B line is written back once (was: 16x write amplification from 8
// incoherent L2s each owning ~2 entries/line). Reads of the full edge list
// are LLC-served after first touch.
__global__ __launch_bounds__(256) void fill_csr_sliced_kernel(
    const int* __restrict__ src, const int* __restrict__ dst,
    int* __restrict__ cursor, int* __restrict__ col,
    int nE, int slice_size)
{
    const int g  = blockIdx.x & 7;    // slice id == XCD id (perf heuristic)
    const int gb = blockIdx.x >> 3;   // block index within group
    const int lo = g * slice_size;
    const int hi = lo + slice_size;
    int e4 = (gb * 256 + (int)threadIdx.x) * 4;
    if (e4 + 3 < nE) {
        int4 d = *(const int4*)(dst + e4);
        bool m0 = (d.x >= lo) & (d.x < hi);
        bool m1 = (d.y >= lo) & (d.y < hi);
        bool m2 = (d.z >= lo) & (d.z < hi);
        bool m3 = (d.w >= lo) & (d.w < hi);
        if (m0 | m1 | m2 | m3) {
            int4 s = *(const int4*)(src + e4);
            if (m0) col[atomicAdd(&cursor[d.x], 1)] = s.x;
            if (m1) col[atomicAdd(&cursor[d.y], 1)] = s.y;
            if (m2) col[atomicAdd(&cursor[d.z], 1)] = s.z;
            if (m3) col[atomicAdd(&cursor[d.w], 1)] = s.w;
        }
    } else if (e4 < nE) {
        for (int e = e4; e < nE; ++e) {
            int dd = dst[e];
            if (dd >= lo && dd < hi) col[atomicAdd(&cursor[dd], 1)] = src[e];
        }
    }
}

// --- fused layer: out = relu?( ((sum_{s in N(i)} h[s] + h[i]) / (deg+1)) @ W + b )
// One wave per node, zero LDS, zero barriers.
// Gather: 16 lanes x float4 over features; 4 edge-subgroups (lane>>4) -> each
// global_load_dwordx4 covers 4 edges (1KB/wave); main loop keeps 4 loads in
// flight into 4 independent float4 accumulators. Tail: pad lanes clamp to the
// last edge, corrected by subtracting pad * h[col[re-1]] afterward. Reduce
// across subgroups via shfl_xor(16,32).
// GEMM: W column `lane` lives in 64 VGPRs; t[k] broadcast via readlane.
__global__ __launch_bounds__(256, 4) void sage_layer_kernel(
    const float* __restrict__ h, const int* __restrict__ row_ptr,
    const int* __restrict__ col, const float* __restrict__ W,
    const float* __restrict__ bias, float* __restrict__ out,
    int N, int do_relu)
{
    const int lane = threadIdx.x & 63;
    const int sub  = lane >> 4;       // edge subgroup 0..3
    const int fq   = lane & 15;       // feature quad (features 4*fq..4*fq+3)
    const int w    = threadIdx.x >> 6;

    // W columns in registers: Wreg[k] = W[k][lane]
    float Wreg[D];
    #pragma unroll
    for (int k = 0; k < D; ++k) Wreg[k] = W[k * D + lane];
    const float bj = bias[lane];

    const float4* __restrict__ h4 = (const float4*)h;   // row i = h4[i*16 + fq]

    const int nwaves = gridDim.x * 4;
    for (int i0 = blockIdx.x * 4 + w; i0 < N; i0 += nwaves) {
        const int i   = __builtin_amdgcn_readfirstlane(i0);
        const int rs  = __builtin_amdgcn_readfirstlane(row_ptr[i]);
        const int re  = __builtin_amdgcn_readfirstlane(row_ptr[i + 1]);
        const int deg = re - rs;

        float4 a0 = {0,0,0,0}, a1 = {0,0,0,0}, a2 = {0,0,0,0}, a3 = {0,0,0,0};

        for (int e0 = rs; e0 < re; e0 += 64) {
            int ee = e0 + lane;
            int idxv = col[(ee < re) ? ee : (re - 1)];   // 64 indices, coalesced
            int rem = re - e0;                            // scalar
            int steps = (((rem < 64) ? rem : 64) + 3) >> 2;  // scalar 1..16
            int t = 0;
            for (; t + 4 <= steps; t += 4) {
                int base = (t << 2) + sub;
                int s0 = __shfl(idxv, base);
                int s1 = __shfl(idxv, base + 4);
                int s2 = __shfl(idxv, base + 8);
                int s3 = __shfl(idxv, base + 12);
                float4 v0 = h4[(size_t)s0 * 16 + fq];
                float4 v1 = h4[(size_t)s1 * 16 + fq];
                float4 v2 = h4[(size_t)s2 * 16 + fq];
                float4 v3 = h4[(size_t)s3 * 16 + fq];
                a0.x += v0.x; a0.y += v0.y; a0.z += v0.z; a0.w += v0.w;
                a1.x += v1.x; a1.y += v1.y; a1.z += v1.z; a1.w += v1.w;
                a2.x += v2.x; a2.y += v2.y; a2.z += v2.z; a2.w += v2.w;
                a3.x += v3.x; a3.y += v3.y; a3.z += v3.z; a3.w += v3.w;
            }
            for (; t < steps; ++t) {
                int s0 = __shfl(idxv, (t << 2) + sub);
                float4 v0 = h4[(size_t)s0 * 16 + fq];
                a0.x += v0.x; a0.y += v0.y; a0.z += v0.z; a0.w += v0.w;
            }
        }

        // combine step accumulators
        float4 tt;
        tt.x = (a0.x + a1.x) + (a2.x + a3.x);
        tt.y = (a0.y + a1.y) + (a2.y + a3.y);
        tt.z = (a0.z + a1.z) + (a2.z + a3.z);
        tt.w = (a0.w + a1.w) + (a2.w + a3.w);
        // reduce across the 4 edge subgroups (lanes l, l^16, l^32, l^48)
        tt.x += __shfl_xor(tt.x, 16); tt.x += __shfl_xor(tt.x, 32);
        tt.y += __shfl_xor(tt.y, 16); tt.y += __shfl_xor(tt.y, 32);
        tt.z += __shfl_xor(tt.z, 16); tt.z += __shfl_xor(tt.z, 32);
        tt.w += __shfl_xor(tt.w, 16); tt.w += __shfl_xor(tt.w, 32);

        // pad correction: clamped lanes duplicated col[re-1] pad times
        int pad = (-deg) & 3;
        if (deg > 0 && pad) {
            int last = __builtin_amdgcn_readfirstlane(col[re - 1]);
            float4 vl = h4[(size_t)last * 16 + fq];
            float fp = (float)pad;
            tt.x = fmaf(-fp, vl.x, tt.x);
            tt.y = fmaf(-fp, vl.y, tt.y);
            tt.z = fmaf(-fp, vl.z, tt.z);
            tt.w = fmaf(-fp, vl.w, tt.w);
        }

        // self term + normalize
        float4 hs = h4[(size_t)i * 16 + fq];
        float invd = 1.0f / (float)(deg + 1);
        tt.x = (tt.x + hs.x) * invd;
        tt.y = (tt.y + hs.y) * invd;
        tt.z = (tt.z + hs.z) * invd;
        tt.w = (tt.w + hs.w) * invd;

        // GEMM: o[lane] = bj + sum_k t[k] * W[k][lane]
        float o = bj;
        #pragma unroll
        for (int k = 0; k < D; ++k) {
            float comp = ((k & 3) == 0) ? tt.x : ((k & 3) == 1) ? tt.y
                       : ((k & 3) == 2) ? tt.z : tt.w;
            int ti = __builtin_amdgcn_readlane(__float_as_int(comp), k >> 2);
            o = fmaf(__int_as_float(ti), Wreg[k], o);
        }
        if (do_relu) o = fmaxf(o, 0.0f);
        out[(size_t)i * D + lane] = o;
    }
}

extern "C" void kernel_launch(void* const* d_in, const int* in_sizes, int n_in,
                              void* d_out, int out_size, void* d_ws, size_t ws_size,
                              hipStream_t stream) {
    const float* x   = (const float*)d_in[0];
    const int*   src = (const int*)d_in[1];
    const int*   dst = (const int*)d_in[2];
    const float* W0  = (const float*)d_in[3];
    const float* b0  = (const float*)d_in[4];
    const float* W1  = (const float*)d_in[5];
    const float* b1  = (const float*)d_in[6];
    const float* W2  = (const float*)d_in[7];
    const float* b2  = (const float*)d_in[8];
    float* out = (float*)d_out;

    const int N = in_sizes[0] / D;   // 50000
    const int E = in_sizes[1];       // 800000

    const int scan_blocks = (N + 255) / 256;  // 196 (<= 256 required by scan_b)

    // workspace: deg | row_ptr | cursor | blocksums | col | h1 | h2
    char* ws = (char*)d_ws;
    size_t off = 0;
    auto alloc = [&](size_t bytes) -> void* {
        void* p = ws + off;
        off = (off + bytes + 255) & ~(size_t)255;
        return p;
    };
    int*   deg       = (int*)  alloc((size_t)N * sizeof(int));
    int*   row_ptr   = (int*)  alloc((size_t)(N + 1) * sizeof(int));
    int*   cursor    = (int*)  alloc((size_t)N * sizeof(int));
    int*   blocksums = (int*)  alloc((size_t)scan_blocks * sizeof(int));
    int*   col       = (int*)  alloc((size_t)E * sizeof(int));
    float* h1        = (float*)alloc((size_t)N * D * sizeof(float));
    float* h2        = (float*)alloc((size_t)N * D * sizeof(float));

    // --- build CSR (once per call; reused by all 3 layers) ---
    hipMemsetAsync(deg, 0, (size_t)N * sizeof(int), stream);
    const int e4_blocks = (E / 4 + 255) / 256;  // 782
    count_deg_kernel<<<e4_blocks, 256, 0, stream>>>(dst, deg, E);
    scan_a_kernel<<<scan_blocks, 256, 0, stream>>>(deg, row_ptr, blocksums, N);
    scan_b_kernel<<<1, 256, 0, stream>>>(blocksums, row_ptr, scan_blocks, N);
    scan_c_kernel<<<scan_blocks, 256, 0, stream>>>(row_ptr, cursor, blocksums, N);
    const int slice_size = (N + 7) / 8;         // 6250
    fill_csr_sliced_kernel<<<e4_blocks * 8, 256, 0, stream>>>(src, dst, cursor, col, E, slice_size);

    const int layer_blocks = 4096;  // no LDS; VGPR-bound occupancy (~16 waves/CU)

    sage_layer_kernel<<<layer_blocks, 256, 0, stream>>>(x,  row_ptr, col, W0, b0, h1,  N, 1);
    sage_layer_kernel<<<layer_blocks, 256, 0, stream>>>(h1, row_ptr, col, W1, b1, h2,  N, 1);
    sage_layer_kernel<<<layer_blocks, 256, 0, stream>>>(h2, row_ptr, col, W2, b2, out, N, 0);
}